// Round 9
// baseline (3624.666 us; speedup 1.0000x reference)
//
#include <hip/hip_runtime.h>

typedef _Float16 half8 __attribute__((ext_vector_type(8)));
typedef __fp16 fp16x2 __attribute__((ext_vector_type(2)));
typedef float floatx4 __attribute__((ext_vector_type(4)));
typedef float f4v __attribute__((ext_vector_type(4)));

// ---------- helpers ----------

__device__ __forceinline__ unsigned fmap(float f) {
    unsigned u = __float_as_uint(f);
    return (u & 0x80000000u) ? ~u : (u | 0x80000000u);
}
__device__ __forceinline__ float funmap(unsigned m) {
    unsigned u = (m & 0x80000000u) ? (m & 0x7FFFFFFFu) : ~m;
    return __uint_as_float(u);
}

__device__ __forceinline__ unsigned long long shfl_xor_u64(unsigned long long v, int mask) {
    unsigned lo = (unsigned)(v & 0xFFFFFFFFu);
    unsigned hi = (unsigned)(v >> 32);
    lo = __shfl_xor(lo, mask, 64);
    hi = __shfl_xor(hi, mask, 64);
    return (((unsigned long long)hi) << 32) | lo;
}

__device__ __forceinline__ half8 nt_load_h8(const half8* p) {
    return __builtin_nontemporal_load(p);
}
__device__ __forceinline__ f4v nt_load_f4(const f4v* p) {
    return __builtin_nontemporal_load(p);
}
__device__ __forceinline__ void nt_store_h8(half8 v, half8* p) {
    __builtin_nontemporal_store(v, p);
}
__device__ __forceinline__ void nt_store_f4(f4v v, f4v* p) {
    __builtin_nontemporal_store(v, p);
}

// Exact two-term split of 8 normalized fp32 values into fp16 hi + scaled lo.
__device__ __forceinline__ void split8(const f4v& v0, const f4v& v1, float rn_,
                                       half8& h, half8& l) {
    float s[8];
    #pragma unroll
    for (int j = 0; j < 4; ++j) { s[j] = v0[j] * rn_; s[4 + j] = v1[j] * rn_; }
    #pragma unroll
    for (int j = 0; j < 8; j += 2) {
        fp16x2 hh = __builtin_amdgcn_cvt_pkrtz(s[j], s[j + 1]);
        h[j] = (_Float16)hh[0]; h[j + 1] = (_Float16)hh[1];
        float r0 = (s[j]     - (float)hh[0]) * 2048.0f;
        float r1 = (s[j + 1] - (float)hh[1]) * 2048.0f;
        fp16x2 ll = __builtin_amdgcn_cvt_pkrtz(r0, r1);
        l[j] = (_Float16)ll[0]; l[j + 1] = (_Float16)ll[1];
    }
}

// ---------- small kernels ----------

__global__ void init_kernel(unsigned long long* packed, unsigned* maxsim,
                            unsigned long long* minall, unsigned long long* minsame,
                            int Q, int B) {
    int i = blockIdx.x * blockDim.x + threadIdx.x;
    if (i < Q) packed[i] = 0ULL;
    if (i < B) { maxsim[i] = 0u; minall[i] = ~0ULL; minsame[i] = ~0ULL; }
}

// One wave per row: rn[row] = 1 / max(||X[row,:256]||, 1e-12)
__global__ void norms_kernel(const float* __restrict__ X, float* __restrict__ rn, int rows) {
    int w = (blockIdx.x * blockDim.x + threadIdx.x) >> 6;
    int lane = threadIdx.x & 63;
    if (w >= rows) return;
    float4 v = *(const float4*)&X[(long)w * 256 + lane * 4];
    float s = v.x * v.x + v.y * v.y + v.z * v.z + v.w * v.w;
    #pragma unroll
    for (int o = 32; o >= 1; o >>= 1) s += __shfl_xor(s, o, 64);
    if (lane == 0) rn[w] = 1.0f / fmaxf(sqrtf(s), 1e-12f);
}

// Normalize + split memory keys into fragment-ordered fp16 hi/lo arrays.
__global__ __launch_bounds__(256) void prep_b(const float* __restrict__ mk,
                                              _Float16* __restrict__ Bh,
                                              _Float16* __restrict__ Bl, int M) {
    __shared__ float tile[16][272];
    __shared__ float rns[16];
    const int mt = blockIdx.x;
    const int m0 = mt << 4;
    const int t = threadIdx.x;

    #pragma unroll
    for (int i = 0; i < 4; ++i) {
        int flat = i * 256 + t;          // 1024 float4 = 16 rows x 64
        int row = flat >> 6;
        int c4 = (flat & 63) << 2;
        f4v f = (f4v){0.f, 0.f, 0.f, 0.f};
        if (m0 + row < M) f = nt_load_f4((const f4v*)&mk[((long)(m0 + row)) * 256 + c4]);
        *(f4v*)&tile[row][c4] = f;
    }
    __syncthreads();

    const int wave = t >> 6, lane = t & 63;
    #pragma unroll
    for (int rr = 0; rr < 4; ++rr) {
        int row = wave * 4 + rr;
        f4v v = *(f4v*)&tile[row][lane << 2];
        float s = v.x * v.x + v.y * v.y + v.z * v.z + v.w * v.w;
        #pragma unroll
        for (int o = 32; o >= 1; o >>= 1) s += __shfl_xor(s, o, 64);
        if (lane == 0) rns[row] = 1.0f / fmaxf(sqrtf(s), 1e-12f);
    }
    __syncthreads();

    #pragma unroll
    for (int i = 0; i < 2; ++i) {
        int fi = i * 256 + t;            // 512 half8 slots: 8 kc x 64 fl
        int kc = fi >> 6;
        int fl = fi & 63;
        int r = fl & 15, sub = fl >> 4;
        int k0 = (kc << 5) + (sub << 3);
        float rn = rns[r];
        f4v v0 = *(f4v*)&tile[r][k0];
        f4v v1 = *(f4v*)&tile[r][k0 + 4];
        half8 h, l;
        split8(v0, v1, rn, h, l);
        long idx = ((long)mt * 8 + kc) * 64 + fl;
        nt_store_h8(h, ((half8*)Bh) + idx);
        nt_store_h8(l, ((half8*)Bl) + idx);
    }
}

// ---------- fused retrieve + update GEMM ----------
// Block: 512 threads (8 waves), owns 2 m-tiles (32 cols). LDS 32 KB ->
// 4 blocks/CU = 32 waves/CU (100% occupancy) at launch_bounds(512,8)
// (VGPR budget 256/wave -> no spill at ~140 live regs).
// Per kc-iter: ONE split + 6 MFMAs, all to DISTINCT accumulators.

__global__ __launch_bounds__(512, 8) void retrieve_fused(
    const float* __restrict__ qf, const float* __restrict__ uf,
    const float* __restrict__ rq, const float* __restrict__ ru,
    const half8* __restrict__ Bh, const half8* __restrict__ Bl,
    const int* __restrict__ mv, const int* __restrict__ lbl,
    unsigned long long* __restrict__ packed,
    unsigned* __restrict__ maxsim, unsigned long long* __restrict__ minall,
    unsigned long long* __restrict__ minsame,
    int M, int Mtiles, int B) {
    __shared__ half8 sB[2][1024];        // [h/l][(nt*8+kc)*64 + lane]  = 32 KB
    const int tid = threadIdx.x;
    const int wave = tid >> 6, lane = tid & 63;
    const int t0 = blockIdx.x << 1;      // first 16-col m-tile of this block
    const int m0 = t0 << 4;

    // stage B tile (fragment order is linear -> coalesced)
    #pragma unroll
    for (int i = 0; i < 2; ++i) {
        int e = i * 512 + tid;           // 1024 half8 entries per array
        int tl = t0 + (e >> 9);
        half8 vh = {0, 0, 0, 0, 0, 0, 0, 0};
        half8 vl = {0, 0, 0, 0, 0, 0, 0, 0};
        if (tl < Mtiles) {
            vh = nt_load_h8(&Bh[(long)t0 * 512 + e]);
            vl = nt_load_h8(&Bl[(long)t0 * 512 + e]);
        }
        sB[0][e] = vh;
        sB[1][e] = vl;
    }
    __syncthreads();

    // ---- retrieve passes: 16 passes x 1 q-tile per wave ----
    #pragma unroll 1
    for (int p = 0; p < 16; ++p) {
        const int qt = p * 8 + wave;
        const int q0 = qt << 4;
        float rn0 = rq[q0 + (lane & 15)];
        const float* p0 = &qf[(long)(q0 + (lane & 15)) * 256 + ((lane >> 4) << 3)];

        floatx4 accH[2], accMa[2], accMb[2];
        #pragma unroll
        for (int nt = 0; nt < 2; ++nt) {
            accH[nt]  = (floatx4){0.f, 0.f, 0.f, 0.f};
            accMa[nt] = (floatx4){0.f, 0.f, 0.f, 0.f};
            accMb[nt] = (floatx4){0.f, 0.f, 0.f, 0.f};
        }

        #pragma unroll
        for (int kc = 0; kc < 8; ++kc) {
            f4v ra = *(const f4v*)(p0 + kc * 32);
            f4v rb = *(const f4v*)(p0 + kc * 32 + 4);
            half8 ah, al;
            split8(ra, rb, rn0, ah, al);
            #pragma unroll
            for (int nt = 0; nt < 2; ++nt) {
                half8 bh = sB[0][(nt * 8 + kc) * 64 + lane];
                half8 bl = sB[1][(nt * 8 + kc) * 64 + lane];
                accH[nt]  = __builtin_amdgcn_mfma_f32_16x16x32_f16(ah, bh, accH[nt],  0, 0, 0);
                accMa[nt] = __builtin_amdgcn_mfma_f32_16x16x32_f16(ah, bl, accMa[nt], 0, 0, 0);
                accMb[nt] = __builtin_amdgcn_mfma_f32_16x16x32_f16(al, bh, accMb[nt], 0, 0, 0);
            }
        }

        unsigned long long best[4];
        #pragma unroll
        for (int r = 0; r < 4; ++r) best[r] = 0ULL;

        #pragma unroll
        for (int nt = 0; nt < 2; ++nt) {
            int mi = m0 + (nt << 4) + (lane & 15);
            if (mi < M) {
                unsigned lowbits = ~(unsigned)mi;
                #pragma unroll
                for (int r = 0; r < 4; ++r) {
                    float s = accH[nt][r] +
                              (accMa[nt][r] + accMb[nt][r]) * (1.0f / 2048.0f);
                    unsigned long long key =
                        (((unsigned long long)fmap(s)) << 32) | lowbits;
                    if (key > best[r]) best[r] = key;
                }
            }
        }
        #pragma unroll
        for (int r = 0; r < 4; ++r) {
            unsigned long long b = best[r];
            #pragma unroll
            for (int o = 1; o < 16; o <<= 1) {
                unsigned long long ob = shfl_xor_u64(b, o);
                if (ob > b) b = ob;
            }
            if ((lane & 15) == 0) {
                int q = qt * 16 + ((lane >> 4) << 2) + r;
                if (b > packed[q]) atomicMax(&packed[q], b);
            }
        }
    }

    // ---- fused update pass: wave w handles update q-tile w ----
    if (wave * 16 < B) {
        const int u0 = wave << 4;
        float rnu = ru[u0 + (lane & 15)];
        const float* pu = &uf[(long)(u0 + (lane & 15)) * 256 + ((lane >> 4) << 3)];

        floatx4 accH[2], accMa[2], accMb[2];
        #pragma unroll
        for (int nt = 0; nt < 2; ++nt) {
            accH[nt]  = (floatx4){0.f, 0.f, 0.f, 0.f};
            accMa[nt] = (floatx4){0.f, 0.f, 0.f, 0.f};
            accMb[nt] = (floatx4){0.f, 0.f, 0.f, 0.f};
        }
        #pragma unroll
        for (int kc = 0; kc < 8; ++kc) {
            f4v ra = *(const f4v*)(pu + kc * 32);
            f4v rb = *(const f4v*)(pu + kc * 32 + 4);
            half8 uh, ul_;
            split8(ra, rb, rnu, uh, ul_);
            #pragma unroll
            for (int nt = 0; nt < 2; ++nt) {
                half8 bh = sB[0][(nt * 8 + kc) * 64 + lane];
                half8 bl = sB[1][(nt * 8 + kc) * 64 + lane];
                accH[nt]  = __builtin_amdgcn_mfma_f32_16x16x32_f16(uh,  bh, accH[nt],  0, 0, 0);
                accMa[nt] = __builtin_amdgcn_mfma_f32_16x16x32_f16(uh,  bl, accMa[nt], 0, 0, 0);
                accMb[nt] = __builtin_amdgcn_mfma_f32_16x16x32_f16(ul_, bh, accMb[nt], 0, 0, 0);
            }
        }
        int lb[4];
        #pragma unroll
        for (int r = 0; r < 4; ++r) lb[r] = lbl[u0 + ((lane >> 4) << 2) + r];

        unsigned bmax[4];
        unsigned long long ball[4], bsame[4];
        #pragma unroll
        for (int r = 0; r < 4; ++r) { bmax[r] = 0u; ball[r] = ~0ULL; bsame[r] = ~0ULL; }

        #pragma unroll
        for (int nt = 0; nt < 2; ++nt) {
            int mi = m0 + (nt << 4) + (lane & 15);
            if (mi < M) {
                int mvv = mv[mi];
                #pragma unroll
                for (int r = 0; r < 4; ++r) {
                    float s = accH[nt][r] + (accMa[nt][r] + accMb[nt][r]) * (1.0f / 2048.0f);
                    unsigned ms = fmap(s);
                    if (ms > bmax[r]) bmax[r] = ms;
                    unsigned long long key = (((unsigned long long)ms) << 32) | (unsigned)mi;
                    if (key < ball[r]) ball[r] = key;
                    if (mvv == lb[r] && key < bsame[r]) bsame[r] = key;
                }
            }
        }
        #pragma unroll
        for (int r = 0; r < 4; ++r) {
            unsigned bm = bmax[r];
            unsigned long long ba = ball[r], bs = bsame[r];
            #pragma unroll
            for (int o = 1; o < 16; o <<= 1) {
                unsigned om = __shfl_xor(bm, o, 64);
                if (om > bm) bm = om;
                unsigned long long oa = shfl_xor_u64(ba, o);
                if (oa < ba) ba = oa;
                unsigned long long os = shfl_xor_u64(bs, o);
                if (os < bs) bs = os;
            }
            if ((lane & 15) == 0) {
                int b = u0 + ((lane >> 4) << 2) + r;
                if (bm > maxsim[b]) atomicMax(&maxsim[b], bm);
                if (ba < minall[b]) atomicMin(&minall[b], ba);
                if (bs < minsame[b]) atomicMin(&minsame[b], bs);
            }
        }
    }
}

// ---------- finish / output kernels ----------

__global__ void finish_retrieve(const unsigned long long* __restrict__ packed,
                                const int* __restrict__ memvals,
                                float* __restrict__ out, int Q) {
    int q = blockIdx.x * blockDim.x + threadIdx.x;
    if (q >= Q) return;
    unsigned long long key = packed[q];
    unsigned m = ~((unsigned)(key & 0xFFFFFFFFu));
    float conf = funmap((unsigned)(key >> 32));
    out[q] = (float)memvals[m];
    out[Q + q] = conf;
}

__global__ void finish_upd(const unsigned* __restrict__ maxsim,
                           const unsigned long long* __restrict__ minall,
                           const unsigned long long* __restrict__ minsame,
                           int* __restrict__ wtgt, int B) {
    __shared__ int tg[256];
    __shared__ unsigned char du[256];
    int b = threadIdx.x;
    int t = -1; bool d = false;
    if (b < B) {
        d = maxsim[b] < fmap(0.8f);
        unsigned long long ks = minsame[b];
        unsigned long long ka = minall[b];
        t = (ks != ~0ULL) ? (int)(ks & 0xFFFFFFFFu) : (int)(ka & 0xFFFFFFFFu);
        tg[b] = t; du[b] = d ? 1 : 0;
    }
    __syncthreads();
    if (b < B) {
        bool win = d;
        if (win)
            for (int b2 = b + 1; b2 < B; ++b2)
                if (du[b2] && tg[b2] == t) { win = false; break; }
        wtgt[b] = win ? t : -1;
    }
}

__global__ void copy_keys(const f4v* __restrict__ src, f4v* __restrict__ dst, long n4) {
    long i = blockIdx.x * (long)blockDim.x + threadIdx.x;
    long stride = (long)gridDim.x * blockDim.x;
    for (; i < n4; i += stride) nt_store_f4(nt_load_f4(&src[i]), &dst[i]);
}

__global__ void copy_vals(const int* __restrict__ src, float* __restrict__ dst, int n) {
    int i = blockIdx.x * blockDim.x + threadIdx.x;
    if (i < n) dst[i] = (float)src[i];
}

__global__ void scatter_kernel(const int* __restrict__ wtgt, const float4* __restrict__ upd4,
                               const int* __restrict__ lbl, float4* __restrict__ keys4,
                               float* __restrict__ vals) {
    int b = blockIdx.x;
    int t = wtgt[b];
    if (t < 0) return;
    int l = threadIdx.x; // 64 threads x float4 = 256 floats
    keys4[(long)t * 64 + l] = upd4[(long)b * 64 + l];
    if (l == 0) vals[t] = (float)lbl[b];
}

// ---------- launch ----------

extern "C" void kernel_launch(void* const* d_in, const int* in_sizes, int n_in,
                              void* d_out, int out_size, void* d_ws, size_t ws_size,
                              hipStream_t stream) {
    const float* qf = (const float*)d_in[0];
    const float* mk = (const float*)d_in[1];
    const int*   mv = (const int*)d_in[2];
    const float* uf = (const float*)d_in[3];
    const int*   ul = (const int*)d_in[4];

    const int D = 256;
    const int Q = in_sizes[0] / D;   // 2048
    const int M = in_sizes[2];       // 100000
    const int B = in_sizes[3] / D;   // 128

    float* out = (float*)d_out;
    float* out_keys = out + 2 * (long)Q;
    float* out_vals = out_keys + (long)M * D;

    // B fragment arrays live in the out_keys region (exact fit). copy_keys
    // overwrites them afterwards.
    _Float16* Bh = (_Float16*)out_keys;
    _Float16* Bl = Bh + (size_t)M * D;

    // Reduction scratch + norms live in the out_vals region (cacheable d_out,
    // unlike d_ws whose reads bypass L2). copy_vals overwrites at the end.
    char* ov = (char*)out_vals;
    unsigned long long* packed  = (unsigned long long*)(ov);            // 16 KB
    unsigned long long* minall  = (unsigned long long*)(ov + 16384);    // 1 KB
    unsigned long long* minsame = (unsigned long long*)(ov + 17408);    // 1 KB
    unsigned* maxsim            = (unsigned*)(ov + 18432);              // 0.5 KB
    float* rq                   = (float*)(ov + 18944);                 // 8 KB
    float* ru                   = (float*)(ov + 27136);                 // 0.5 KB

    // d_ws only holds atomic-free, rarely-touched data.
    int* wtgt = (int*)d_ws;

    const int Mtiles = (M + 15) / 16;          // 6250
    const int grid_g = (Mtiles + 1) / 2;       // 3125

    int initN = (Q > B ? Q : B);
    init_kernel<<<(initN + 255) / 256, 256, 0, stream>>>(packed, maxsim, minall, minsame, Q, B);

    norms_kernel<<<(Q + 3) / 4, 256, 0, stream>>>(qf, rq, Q);
    norms_kernel<<<(B + 3) / 4, 256, 0, stream>>>(uf, ru, B);

    prep_b<<<Mtiles, 256, 0, stream>>>(mk, Bh, Bl, M);

    retrieve_fused<<<grid_g, 512, 0, stream>>>(
        qf, uf, rq, ru, (const half8*)Bh, (const half8*)Bl, mv, ul,
        packed, maxsim, minall, minsame, M, Mtiles, B);

    finish_retrieve<<<(Q + 255) / 256, 256, 0, stream>>>(packed, mv, out, Q);
    finish_upd<<<1, B, 0, stream>>>(maxsim, minall, minsame, wtgt, B);

    // Overwrite scratch regions with the real outputs (stream-ordered).
    copy_keys<<<2048, 256, 0, stream>>>((const f4v*)mk, (f4v*)out_keys, (long)M * (D / 4));
    copy_vals<<<(M + 255) / 256, 256, 0, stream>>>(mv, out_vals, M);
    scatter_kernel<<<B, 64, 0, stream>>>(wtgt, (const float4*)uf, ul, (float4*)out_keys, out_vals);
}

// Round 10
// 2236.260 us; speedup vs baseline: 1.6209x; 1.6209x over previous
//
#include <hip/hip_runtime.h>

typedef _Float16 half8 __attribute__((ext_vector_type(8)));
typedef __fp16 fp16x2 __attribute__((ext_vector_type(2)));
typedef float floatx4 __attribute__((ext_vector_type(4)));
typedef float f4v __attribute__((ext_vector_type(4)));

// ---------- helpers ----------

__device__ __forceinline__ unsigned fmap(float f) {
    unsigned u = __float_as_uint(f);
    return (u & 0x80000000u) ? ~u : (u | 0x80000000u);
}
__device__ __forceinline__ float funmap(unsigned m) {
    unsigned u = (m & 0x80000000u) ? (m & 0x7FFFFFFFu) : ~m;
    return __uint_as_float(u);
}

__device__ __forceinline__ unsigned long long shfl_xor_u64(unsigned long long v, int mask) {
    unsigned lo = (unsigned)(v & 0xFFFFFFFFu);
    unsigned hi = (unsigned)(v >> 32);
    lo = __shfl_xor(lo, mask, 64);
    hi = __shfl_xor(hi, mask, 64);
    return (((unsigned long long)hi) << 32) | lo;
}

__device__ __forceinline__ half8 nt_load_h8(const half8* p) {
    return __builtin_nontemporal_load(p);
}
__device__ __forceinline__ f4v nt_load_f4(const f4v* p) {
    return __builtin_nontemporal_load(p);
}
__device__ __forceinline__ void nt_store_h8(half8 v, half8* p) {
    __builtin_nontemporal_store(v, p);
}
__device__ __forceinline__ void nt_store_f4(f4v v, f4v* p) {
    __builtin_nontemporal_store(v, p);
}

// Exact two-term split WITH row-scale (used for B / memory keys).
__device__ __forceinline__ void split8n(const f4v& v0, const f4v& v1, float rn_,
                                        half8& h, half8& l) {
    float s[8];
    #pragma unroll
    for (int j = 0; j < 4; ++j) { s[j] = v0[j] * rn_; s[4 + j] = v1[j] * rn_; }
    #pragma unroll
    for (int j = 0; j < 8; j += 2) {
        fp16x2 hh = __builtin_amdgcn_cvt_pkrtz(s[j], s[j + 1]);
        h[j] = (_Float16)hh[0]; h[j + 1] = (_Float16)hh[1];
        float r0 = (s[j]     - (float)hh[0]) * 2048.0f;
        float r1 = (s[j + 1] - (float)hh[1]) * 2048.0f;
        fp16x2 ll = __builtin_amdgcn_cvt_pkrtz(r0, r1);
        l[j] = (_Float16)ll[0]; l[j + 1] = (_Float16)ll[1];
    }
}

// Exact two-term split WITHOUT scaling (used for A / queries & updates).
// Row norm rn_q is a positive per-row constant -> argmax/argmin over m are
// invariant; the scale is applied in the finish kernels.
__device__ __forceinline__ void split8r(const f4v& v0, const f4v& v1,
                                        half8& h, half8& l) {
    #pragma unroll
    for (int j = 0; j < 4; j += 2) {
        fp16x2 hh = __builtin_amdgcn_cvt_pkrtz(v0[j], v0[j + 1]);
        h[j] = (_Float16)hh[0]; h[j + 1] = (_Float16)hh[1];
        float r0 = (v0[j]     - (float)hh[0]) * 2048.0f;
        float r1 = (v0[j + 1] - (float)hh[1]) * 2048.0f;
        fp16x2 ll = __builtin_amdgcn_cvt_pkrtz(r0, r1);
        l[j] = (_Float16)ll[0]; l[j + 1] = (_Float16)ll[1];
    }
    #pragma unroll
    for (int j = 0; j < 4; j += 2) {
        fp16x2 hh = __builtin_amdgcn_cvt_pkrtz(v1[j], v1[j + 1]);
        h[4 + j] = (_Float16)hh[0]; h[4 + j + 1] = (_Float16)hh[1];
        float r0 = (v1[j]     - (float)hh[0]) * 2048.0f;
        float r1 = (v1[j + 1] - (float)hh[1]) * 2048.0f;
        fp16x2 ll = __builtin_amdgcn_cvt_pkrtz(r0, r1);
        l[4 + j] = (_Float16)ll[0]; l[4 + j + 1] = (_Float16)ll[1];
    }
}

// ---------- small kernels ----------

__global__ void init_kernel(unsigned long long* packed, unsigned* maxsim,
                            unsigned long long* minall, unsigned long long* minsame,
                            int Q, int B) {
    int i = blockIdx.x * blockDim.x + threadIdx.x;
    if (i < Q) packed[i] = 0ULL;
    if (i < B) { maxsim[i] = 0u; minall[i] = ~0ULL; minsame[i] = ~0ULL; }
}

// One wave per row: rn[row] = 1 / max(||X[row,:256]||, 1e-12)
__global__ void norms_kernel(const float* __restrict__ X, float* __restrict__ rn, int rows) {
    int w = (blockIdx.x * blockDim.x + threadIdx.x) >> 6;
    int lane = threadIdx.x & 63;
    if (w >= rows) return;
    float4 v = *(const float4*)&X[(long)w * 256 + lane * 4];
    float s = v.x * v.x + v.y * v.y + v.z * v.z + v.w * v.w;
    #pragma unroll
    for (int o = 32; o >= 1; o >>= 1) s += __shfl_xor(s, o, 64);
    if (lane == 0) rn[w] = 1.0f / fmaxf(sqrtf(s), 1e-12f);
}

// Normalize + split memory keys into fragment-ordered fp16 hi/lo arrays.
__global__ __launch_bounds__(256) void prep_b(const float* __restrict__ mk,
                                              _Float16* __restrict__ Bh,
                                              _Float16* __restrict__ Bl, int M) {
    __shared__ float tile[16][272];
    __shared__ float rns[16];
    const int mt = blockIdx.x;
    const int m0 = mt << 4;
    const int t = threadIdx.x;

    #pragma unroll
    for (int i = 0; i < 4; ++i) {
        int flat = i * 256 + t;          // 1024 float4 = 16 rows x 64
        int row = flat >> 6;
        int c4 = (flat & 63) << 2;
        f4v f = (f4v){0.f, 0.f, 0.f, 0.f};
        if (m0 + row < M) f = nt_load_f4((const f4v*)&mk[((long)(m0 + row)) * 256 + c4]);
        *(f4v*)&tile[row][c4] = f;
    }
    __syncthreads();

    const int wave = t >> 6, lane = t & 63;
    #pragma unroll
    for (int rr = 0; rr < 4; ++rr) {
        int row = wave * 4 + rr;
        f4v v = *(f4v*)&tile[row][lane << 2];
        float s = v.x * v.x + v.y * v.y + v.z * v.z + v.w * v.w;
        #pragma unroll
        for (int o = 32; o >= 1; o >>= 1) s += __shfl_xor(s, o, 64);
        if (lane == 0) rns[row] = 1.0f / fmaxf(sqrtf(s), 1e-12f);
    }
    __syncthreads();

    #pragma unroll
    for (int i = 0; i < 2; ++i) {
        int fi = i * 256 + t;            // 512 half8 slots: 8 kc x 64 fl
        int kc = fi >> 6;
        int fl = fi & 63;
        int r = fl & 15, sub = fl >> 4;
        int k0 = (kc << 5) + (sub << 3);
        float rn = rns[r];
        f4v v0 = *(f4v*)&tile[r][k0];
        f4v v1 = *(f4v*)&tile[r][k0 + 4];
        half8 h, l;
        split8n(v0, v1, rn, h, l);
        long idx = ((long)mt * 8 + kc) * 64 + fl;
        nt_store_h8(h, ((half8*)Bh) + idx);
        nt_store_h8(l, ((half8*)Bl) + idx);
    }
}

// ---------- fused retrieve + update GEMM (R5 geometry, reordered MFMAs) ----------
// Block: 512 threads (8 waves), owns 4 m-tiles (64 cols). LDS 64 KB -> 2 blocks/CU.
// Dependent accM writes separated by one nt-group via a rotated bh register.

__global__ __launch_bounds__(512, 4) void retrieve_fused(
    const float* __restrict__ qf, const float* __restrict__ uf,
    const half8* __restrict__ Bh, const half8* __restrict__ Bl,
    const int* __restrict__ mv, const int* __restrict__ lbl,
    unsigned long long* __restrict__ packed,
    unsigned* __restrict__ maxsim, unsigned long long* __restrict__ minall,
    unsigned long long* __restrict__ minsame,
    int M, int Mtiles, int B) {
    __shared__ half8 sB[2][2048];        // [h/l][(nt*8+kc)*64 + lane]  = 64 KB
    const int tid = threadIdx.x;
    const int wave = tid >> 6, lane = tid & 63;
    const int t0 = blockIdx.x << 2;      // first 16-col m-tile of this block
    const int m0 = t0 << 4;

    // stage B tile (fragment order is linear -> coalesced)
    #pragma unroll
    for (int i = 0; i < 4; ++i) {
        int e = i * 512 + tid;           // 2048 half8 entries per array
        int tl = t0 + (e >> 9);
        half8 vh = {0, 0, 0, 0, 0, 0, 0, 0};
        half8 vl = {0, 0, 0, 0, 0, 0, 0, 0};
        if (tl < Mtiles) {
            vh = nt_load_h8(&Bh[(long)t0 * 512 + e]);
            vl = nt_load_h8(&Bl[(long)t0 * 512 + e]);
        }
        sB[0][e] = vh;
        sB[1][e] = vl;
    }
    __syncthreads();

    // ---- retrieve passes: 8 passes x 2 q-tiles per wave ----
    for (int p = 0; p < 8; ++p) {
        const int qt0 = (p * 8 + wave) * 2;
        const int q0 = qt0 << 4;
        const float* p0 = &qf[(long)(q0 + (lane & 15)) * 256 + ((lane >> 4) << 3)];
        const float* p1 = p0 + 16 * 256;

        floatx4 accH[2][4], accM[2][4];
        #pragma unroll
        for (int tq = 0; tq < 2; ++tq)
            #pragma unroll
            for (int nt = 0; nt < 4; ++nt) {
                accH[tq][nt] = (floatx4){0.f, 0.f, 0.f, 0.f};
                accM[tq][nt] = (floatx4){0.f, 0.f, 0.f, 0.f};
            }

        f4v r0a = *(const f4v*)p0, r0b = *(const f4v*)(p0 + 4);
        f4v r1a = *(const f4v*)p1, r1b = *(const f4v*)(p1 + 4);

        for (int kc = 0; kc < 8; ++kc) {
            f4v n0a, n0b, n1a, n1b;
            if (kc < 7) {
                const float* q0p = p0 + (kc + 1) * 32;
                const float* q1p = p1 + (kc + 1) * 32;
                n0a = *(const f4v*)q0p; n0b = *(const f4v*)(q0p + 4);
                n1a = *(const f4v*)q1p; n1b = *(const f4v*)(q1p + 4);
            }
            half8 a0h, a0l, a1h, a1l;
            split8r(r0a, r0b, a0h, a0l);
            split8r(r1a, r1b, a1h, a1l);

            // Reordered MFMA schedule: per nt issue the independent set
            // {H0, M0+=a0h*bl, H1, M1+=a1h*bl}, then the dependent
            // {M0+=a0l*bh_prev, M1+=a1l*bh_prev} for the PREVIOUS nt —
            // dependent writes to the same accM are >=6 MFMAs apart.
            half8 bh_prev;
            #pragma unroll
            for (int nt = 0; nt < 4; ++nt) {
                half8 bh = sB[0][(nt * 8 + kc) * 64 + lane];
                half8 bl = sB[1][(nt * 8 + kc) * 64 + lane];
                accH[0][nt] = __builtin_amdgcn_mfma_f32_16x16x32_f16(a0h, bh, accH[0][nt], 0, 0, 0);
                accM[0][nt] = __builtin_amdgcn_mfma_f32_16x16x32_f16(a0h, bl, accM[0][nt], 0, 0, 0);
                accH[1][nt] = __builtin_amdgcn_mfma_f32_16x16x32_f16(a1h, bh, accH[1][nt], 0, 0, 0);
                accM[1][nt] = __builtin_amdgcn_mfma_f32_16x16x32_f16(a1h, bl, accM[1][nt], 0, 0, 0);
                if (nt > 0) {
                    accM[0][nt - 1] = __builtin_amdgcn_mfma_f32_16x16x32_f16(a0l, bh_prev, accM[0][nt - 1], 0, 0, 0);
                    accM[1][nt - 1] = __builtin_amdgcn_mfma_f32_16x16x32_f16(a1l, bh_prev, accM[1][nt - 1], 0, 0, 0);
                }
                bh_prev = bh;
            }
            accM[0][3] = __builtin_amdgcn_mfma_f32_16x16x32_f16(a0l, bh_prev, accM[0][3], 0, 0, 0);
            accM[1][3] = __builtin_amdgcn_mfma_f32_16x16x32_f16(a1l, bh_prev, accM[1][3], 0, 0, 0);

            r0a = n0a; r0b = n0b; r1a = n1a; r1b = n1b;
        }

        unsigned long long best[2][4];
        #pragma unroll
        for (int tq = 0; tq < 2; ++tq)
            #pragma unroll
            for (int r = 0; r < 4; ++r) best[tq][r] = 0ULL;

        #pragma unroll
        for (int nt = 0; nt < 4; ++nt) {
            int mi = m0 + (nt << 4) + (lane & 15);
            if (mi < M) {
                unsigned lowbits = ~(unsigned)mi;
                #pragma unroll
                for (int tq = 0; tq < 2; ++tq)
                    #pragma unroll
                    for (int r = 0; r < 4; ++r) {
                        float s = accH[tq][nt][r] + accM[tq][nt][r] * (1.0f / 2048.0f);
                        unsigned long long key =
                            (((unsigned long long)fmap(s)) << 32) | lowbits;
                        if (key > best[tq][r]) best[tq][r] = key;
                    }
            }
        }
        #pragma unroll
        for (int tq = 0; tq < 2; ++tq)
            #pragma unroll
            for (int r = 0; r < 4; ++r) {
                unsigned long long b = best[tq][r];
                #pragma unroll
                for (int o = 1; o < 16; o <<= 1) {
                    unsigned long long ob = shfl_xor_u64(b, o);
                    if (ob > b) b = ob;
                }
                if ((lane & 15) == 0) {
                    int q = (qt0 + tq) * 16 + ((lane >> 4) << 2) + r;
                    if (b > packed[q]) atomicMax(&packed[q], b);
                }
            }
    }

    // ---- fused update pass: wave w handles update q-tile w ----
    if (wave * 16 < B) {
        const int u0 = wave << 4;
        const float* pu = &uf[(long)(u0 + (lane & 15)) * 256 + ((lane >> 4) << 3)];

        floatx4 accH[4], accM[4];
        #pragma unroll
        for (int nt = 0; nt < 4; ++nt) {
            accH[nt] = (floatx4){0.f, 0.f, 0.f, 0.f};
            accM[nt] = (floatx4){0.f, 0.f, 0.f, 0.f};
        }
        f4v ra = *(const f4v*)pu, rb = *(const f4v*)(pu + 4);
        for (int kc = 0; kc < 8; ++kc) {
            f4v na, nb;
            if (kc < 7) {
                const float* qp = pu + (kc + 1) * 32;
                na = *(const f4v*)qp; nb = *(const f4v*)(qp + 4);
            }
            half8 uh, ul_;
            split8r(ra, rb, uh, ul_);
            half8 bh_prev;
            #pragma unroll
            for (int nt = 0; nt < 4; ++nt) {
                half8 bh = sB[0][(nt * 8 + kc) * 64 + lane];
                half8 bl = sB[1][(nt * 8 + kc) * 64 + lane];
                accH[nt] = __builtin_amdgcn_mfma_f32_16x16x32_f16(uh, bh, accH[nt], 0, 0, 0);
                accM[nt] = __builtin_amdgcn_mfma_f32_16x16x32_f16(uh, bl, accM[nt], 0, 0, 0);
                if (nt > 0)
                    accM[nt - 1] = __builtin_amdgcn_mfma_f32_16x16x32_f16(ul_, bh_prev, accM[nt - 1], 0, 0, 0);
                bh_prev = bh;
            }
            accM[3] = __builtin_amdgcn_mfma_f32_16x16x32_f16(ul_, bh_prev, accM[3], 0, 0, 0);
            ra = na; rb = nb;
        }
        int lb[4];
        #pragma unroll
        for (int r = 0; r < 4; ++r) lb[r] = lbl[u0 + ((lane >> 4) << 2) + r];

        unsigned bmax[4];
        unsigned long long ball[4], bsame[4];
        #pragma unroll
        for (int r = 0; r < 4; ++r) { bmax[r] = 0u; ball[r] = ~0ULL; bsame[r] = ~0ULL; }

        #pragma unroll
        for (int nt = 0; nt < 4; ++nt) {
            int mi = m0 + (nt << 4) + (lane & 15);
            if (mi < M) {
                int mvv = mv[mi];
                #pragma unroll
                for (int r = 0; r < 4; ++r) {
                    float s = accH[nt][r] + accM[nt][r] * (1.0f / 2048.0f);
                    unsigned ms = fmap(s);
                    if (ms > bmax[r]) bmax[r] = ms;
                    unsigned long long key = (((unsigned long long)ms) << 32) | (unsigned)mi;
                    if (key < ball[r]) ball[r] = key;
                    if (mvv == lb[r] && key < bsame[r]) bsame[r] = key;
                }
            }
        }
        #pragma unroll
        for (int r = 0; r < 4; ++r) {
            unsigned bm = bmax[r];
            unsigned long long ba = ball[r], bs = bsame[r];
            #pragma unroll
            for (int o = 1; o < 16; o <<= 1) {
                unsigned om = __shfl_xor(bm, o, 64);
                if (om > bm) bm = om;
                unsigned long long oa = shfl_xor_u64(ba, o);
                if (oa < ba) ba = oa;
                unsigned long long os = shfl_xor_u64(bs, o);
                if (os < bs) bs = os;
            }
            if ((lane & 15) == 0) {
                int b = u0 + ((lane >> 4) << 2) + r;
                if (bm > maxsim[b]) atomicMax(&maxsim[b], bm);
                if (ba < minall[b]) atomicMin(&minall[b], ba);
                if (bs < minsame[b]) atomicMin(&minsame[b], bs);
            }
        }
    }
}

// ---------- finish / output kernels ----------

__global__ void finish_retrieve(const unsigned long long* __restrict__ packed,
                                const int* __restrict__ memvals,
                                const float* __restrict__ rq,
                                float* __restrict__ out, int Q) {
    int q = blockIdx.x * blockDim.x + threadIdx.x;
    if (q >= Q) return;
    unsigned long long key = packed[q];
    unsigned m = ~((unsigned)(key & 0xFFFFFFFFu));
    float conf = funmap((unsigned)(key >> 32)) * rq[q];   // apply row norm here
    out[q] = (float)memvals[m];
    out[Q + q] = conf;
}

__global__ void finish_upd(const unsigned* __restrict__ maxsim,
                           const unsigned long long* __restrict__ minall,
                           const unsigned long long* __restrict__ minsame,
                           const float* __restrict__ ru,
                           int* __restrict__ wtgt, int B) {
    __shared__ int tg[256];
    __shared__ unsigned char du[256];
    int b = threadIdx.x;
    int t = -1; bool d = false;
    if (b < B) {
        d = funmap(maxsim[b]) * ru[b] < 0.8f;             // apply row norm here
        unsigned long long ks = minsame[b];
        unsigned long long ka = minall[b];
        t = (ks != ~0ULL) ? (int)(ks & 0xFFFFFFFFu) : (int)(ka & 0xFFFFFFFFu);
        tg[b] = t; du[b] = d ? 1 : 0;
    }
    __syncthreads();
    if (b < B) {
        bool win = d;
        if (win)
            for (int b2 = b + 1; b2 < B; ++b2)
                if (du[b2] && tg[b2] == t) { win = false; break; }
        wtgt[b] = win ? t : -1;
    }
}

__global__ void copy_keys(const f4v* __restrict__ src, f4v* __restrict__ dst, long n4) {
    long i = blockIdx.x * (long)blockDim.x + threadIdx.x;
    long stride = (long)gridDim.x * blockDim.x;
    for (; i < n4; i += stride) nt_store_f4(nt_load_f4(&src[i]), &dst[i]);
}

__global__ void copy_vals(const int* __restrict__ src, float* __restrict__ dst, int n) {
    int i = blockIdx.x * blockDim.x + threadIdx.x;
    if (i < n) dst[i] = (float)src[i];
}

__global__ void scatter_kernel(const int* __restrict__ wtgt, const float4* __restrict__ upd4,
                               const int* __restrict__ lbl, float4* __restrict__ keys4,
                               float* __restrict__ vals) {
    int b = blockIdx.x;
    int t = wtgt[b];
    if (t < 0) return;
    int l = threadIdx.x; // 64 threads x float4 = 256 floats
    keys4[(long)t * 64 + l] = upd4[(long)b * 64 + l];
    if (l == 0) vals[t] = (float)lbl[b];
}

// ---------- launch ----------

extern "C" void kernel_launch(void* const* d_in, const int* in_sizes, int n_in,
                              void* d_out, int out_size, void* d_ws, size_t ws_size,
                              hipStream_t stream) {
    const float* qf = (const float*)d_in[0];
    const float* mk = (const float*)d_in[1];
    const int*   mv = (const int*)d_in[2];
    const float* uf = (const float*)d_in[3];
    const int*   ul = (const int*)d_in[4];

    const int D = 256;
    const int Q = in_sizes[0] / D;   // 2048
    const int M = in_sizes[2];       // 100000
    const int B = in_sizes[3] / D;   // 128

    float* out = (float*)d_out;
    float* out_keys = out + 2 * (long)Q;
    float* out_vals = out_keys + (long)M * D;

    // B fragment arrays live in the out_keys region (exact fit). copy_keys
    // overwrites them afterwards.
    _Float16* Bh = (_Float16*)out_keys;
    _Float16* Bl = Bh + (size_t)M * D;

    // Reduction scratch + norms live in the out_vals region (cacheable d_out,
    // unlike d_ws whose reads bypass L2). copy_vals overwrites at the end.
    char* ov = (char*)out_vals;
    unsigned long long* packed  = (unsigned long long*)(ov);            // 16 KB
    unsigned long long* minall  = (unsigned long long*)(ov + 16384);    // 1 KB
    unsigned long long* minsame = (unsigned long long*)(ov + 17408);    // 1 KB
    unsigned* maxsim            = (unsigned*)(ov + 18432);              // 0.5 KB
    float* rq                   = (float*)(ov + 18944);                 // 8 KB
    float* ru                   = (float*)(ov + 27136);                 // 0.5 KB

    // d_ws only holds atomic-free, rarely-touched data.
    int* wtgt = (int*)d_ws;

    const int Mtiles = (M + 15) / 16;          // 6250
    const int grid_g = (Mtiles + 3) / 4;       // 1563

    int initN = (Q > B ? Q : B);
    init_kernel<<<(initN + 255) / 256, 256, 0, stream>>>(packed, maxsim, minall, minsame, Q, B);

    norms_kernel<<<(Q + 3) / 4, 256, 0, stream>>>(qf, rq, Q);
    norms_kernel<<<(B + 3) / 4, 256, 0, stream>>>(uf, ru, B);

    prep_b<<<Mtiles, 256, 0, stream>>>(mk, Bh, Bl, M);

    retrieve_fused<<<grid_g, 512, 0, stream>>>(
        qf, uf, (const half8*)Bh, (const half8*)Bl, mv, ul,
        packed, maxsim, minall, minsame, M, Mtiles, B);

    finish_retrieve<<<(Q + 255) / 256, 256, 0, stream>>>(packed, mv, rq, out, Q);
    finish_upd<<<1, B, 0, stream>>>(maxsim, minall, minsame, ru, wtgt, B);

    // Overwrite scratch regions with the real outputs (stream-ordered).
    copy_keys<<<2048, 256, 0, stream>>>((const f4v*)mk, (f4v*)out_keys, (long)M * (D / 4));
    copy_vals<<<(M + 255) / 256, 256, 0, stream>>>(mv, out_vals, M);
    scatter_kernel<<<B, 64, 0, stream>>>(wtgt, (const float4*)uf, ul, (float4*)out_keys, out_vals);
}

// Round 11
// 1973.602 us; speedup vs baseline: 1.8366x; 1.1331x over previous
//
#include <hip/hip_runtime.h>

typedef _Float16 half8 __attribute__((ext_vector_type(8)));
typedef __fp16 fp16x2 __attribute__((ext_vector_type(2)));
typedef float floatx4 __attribute__((ext_vector_type(4)));
typedef float f4v __attribute__((ext_vector_type(4)));

// ---------- helpers ----------

__device__ __forceinline__ unsigned fmap(float f) {
    unsigned u = __float_as_uint(f);
    return (u & 0x80000000u) ? ~u : (u | 0x80000000u);
}
__device__ __forceinline__ float funmap(unsigned m) {
    unsigned u = (m & 0x80000000u) ? (m & 0x7FFFFFFFu) : ~m;
    return __uint_as_float(u);
}

__device__ __forceinline__ unsigned long long shfl_xor_u64(unsigned long long v, int mask) {
    unsigned lo = (unsigned)(v & 0xFFFFFFFFu);
    unsigned hi = (unsigned)(v >> 32);
    lo = __shfl_xor(lo, mask, 64);
    hi = __shfl_xor(hi, mask, 64);
    return (((unsigned long long)hi) << 32) | lo;
}

__device__ __forceinline__ half8 nt_load_h8(const half8* p) {
    return __builtin_nontemporal_load(p);
}
__device__ __forceinline__ f4v nt_load_f4(const f4v* p) {
    return __builtin_nontemporal_load(p);
}
__device__ __forceinline__ void nt_store_h8(half8 v, half8* p) {
    __builtin_nontemporal_store(v, p);
}
__device__ __forceinline__ void nt_store_f4(f4v v, f4v* p) {
    __builtin_nontemporal_store(v, p);
}

// Exact two-term split WITH row-scale (used for B / memory keys).
__device__ __forceinline__ void split8n(const f4v& v0, const f4v& v1, float rn_,
                                        half8& h, half8& l) {
    float s[8];
    #pragma unroll
    for (int j = 0; j < 4; ++j) { s[j] = v0[j] * rn_; s[4 + j] = v1[j] * rn_; }
    #pragma unroll
    for (int j = 0; j < 8; j += 2) {
        fp16x2 hh = __builtin_amdgcn_cvt_pkrtz(s[j], s[j + 1]);
        h[j] = (_Float16)hh[0]; h[j + 1] = (_Float16)hh[1];
        float r0 = (s[j]     - (float)hh[0]) * 2048.0f;
        float r1 = (s[j + 1] - (float)hh[1]) * 2048.0f;
        fp16x2 ll = __builtin_amdgcn_cvt_pkrtz(r0, r1);
        l[j] = (_Float16)ll[0]; l[j + 1] = (_Float16)ll[1];
    }
}

// Exact two-term split WITHOUT scaling (used for A / queries & updates).
// Row norm is a positive per-row constant -> argmax/argmin over m invariant;
// the scale is applied in the finish kernels.
__device__ __forceinline__ void split8r(const f4v& v0, const f4v& v1,
                                        half8& h, half8& l) {
    #pragma unroll
    for (int j = 0; j < 4; j += 2) {
        fp16x2 hh = __builtin_amdgcn_cvt_pkrtz(v0[j], v0[j + 1]);
        h[j] = (_Float16)hh[0]; h[j + 1] = (_Float16)hh[1];
        float r0 = (v0[j]     - (float)hh[0]) * 2048.0f;
        float r1 = (v0[j + 1] - (float)hh[1]) * 2048.0f;
        fp16x2 ll = __builtin_amdgcn_cvt_pkrtz(r0, r1);
        l[j] = (_Float16)ll[0]; l[j + 1] = (_Float16)ll[1];
    }
    #pragma unroll
    for (int j = 0; j < 4; j += 2) {
        fp16x2 hh = __builtin_amdgcn_cvt_pkrtz(v1[j], v1[j + 1]);
        h[4 + j] = (_Float16)hh[0]; h[4 + j + 1] = (_Float16)hh[1];
        float r0 = (v1[j]     - (float)hh[0]) * 2048.0f;
        float r1 = (v1[j + 1] - (float)hh[1]) * 2048.0f;
        fp16x2 ll = __builtin_amdgcn_cvt_pkrtz(r0, r1);
        l[4 + j] = (_Float16)ll[0]; l[4 + j + 1] = (_Float16)ll[1];
    }
}

// ---------- small kernels ----------

__global__ void init_kernel(unsigned long long* packed, unsigned* maxsim,
                            unsigned long long* minall, unsigned long long* minsame,
                            int Q, int B) {
    int i = blockIdx.x * blockDim.x + threadIdx.x;
    if (i < Q) packed[i] = 0ULL;
    if (i < B) { maxsim[i] = 0u; minall[i] = ~0ULL; minsame[i] = ~0ULL; }
}

// One wave per row: rn[row] = 1 / max(||X[row,:256]||, 1e-12)
__global__ void norms_kernel(const float* __restrict__ X, float* __restrict__ rn, int rows) {
    int w = (blockIdx.x * blockDim.x + threadIdx.x) >> 6;
    int lane = threadIdx.x & 63;
    if (w >= rows) return;
    float4 v = *(const float4*)&X[(long)w * 256 + lane * 4];
    float s = v.x * v.x + v.y * v.y + v.z * v.z + v.w * v.w;
    #pragma unroll
    for (int o = 32; o >= 1; o >>= 1) s += __shfl_xor(s, o, 64);
    if (lane == 0) rn[w] = 1.0f / fmaxf(sqrtf(s), 1e-12f);
}

// Normalize + split memory keys into fragment-ordered fp16 hi/lo arrays.
__global__ __launch_bounds__(256) void prep_b(const float* __restrict__ mk,
                                              _Float16* __restrict__ Bh,
                                              _Float16* __restrict__ Bl, int M) {
    __shared__ float tile[16][272];
    __shared__ float rns[16];
    const int mt = blockIdx.x;
    const int m0 = mt << 4;
    const int t = threadIdx.x;

    #pragma unroll
    for (int i = 0; i < 4; ++i) {
        int flat = i * 256 + t;          // 1024 float4 = 16 rows x 64
        int row = flat >> 6;
        int c4 = (flat & 63) << 2;
        f4v f = (f4v){0.f, 0.f, 0.f, 0.f};
        if (m0 + row < M) f = nt_load_f4((const f4v*)&mk[((long)(m0 + row)) * 256 + c4]);
        *(f4v*)&tile[row][c4] = f;
    }
    __syncthreads();

    const int wave = t >> 6, lane = t & 63;
    #pragma unroll
    for (int rr = 0; rr < 4; ++rr) {
        int row = wave * 4 + rr;
        f4v v = *(f4v*)&tile[row][lane << 2];
        float s = v.x * v.x + v.y * v.y + v.z * v.z + v.w * v.w;
        #pragma unroll
        for (int o = 32; o >= 1; o >>= 1) s += __shfl_xor(s, o, 64);
        if (lane == 0) rns[row] = 1.0f / fmaxf(sqrtf(s), 1e-12f);
    }
    __syncthreads();

    #pragma unroll
    for (int i = 0; i < 2; ++i) {
        int fi = i * 256 + t;            // 512 half8 slots: 8 kc x 64 fl
        int kc = fi >> 6;
        int fl = fi & 63;
        int r = fl & 15, sub = fl >> 4;
        int k0 = (kc << 5) + (sub << 3);
        float rn = rns[r];
        f4v v0 = *(f4v*)&tile[r][k0];
        f4v v1 = *(f4v*)&tile[r][k0 + 4];
        half8 h, l;
        split8n(v0, v1, rn, h, l);
        long idx = ((long)mt * 8 + kc) * 64 + fl;
        nt_store_h8(h, ((half8*)Bh) + idx);
        nt_store_h8(l, ((half8*)Bl) + idx);
    }
}

// ---------- fused retrieve + update GEMM ----------
// Block: 512 threads (8 waves), owns 4 m-tiles (64 cols). LDS 64 KB.
// launch_bounds(512,2): 256-reg/wave budget -> the 3-accumulator-set schedule
// (24 independent MFMAs per kc-iter, ~180 live regs) fits with NO spill.
// 1 block/CU, 2 waves/SIMD; dep-free MFMA bursts keep the matrix pipe fed.

__global__ __launch_bounds__(512, 2) void retrieve_fused(
    const float* __restrict__ qf, const float* __restrict__ uf,
    const half8* __restrict__ Bh, const half8* __restrict__ Bl,
    const int* __restrict__ mv, const int* __restrict__ lbl,
    unsigned long long* __restrict__ packed,
    unsigned* __restrict__ maxsim, unsigned long long* __restrict__ minall,
    unsigned long long* __restrict__ minsame,
    int M, int Mtiles, int B) {
    __shared__ half8 sB[2][2048];        // [h/l][(nt*8+kc)*64 + lane]  = 64 KB
    const int tid = threadIdx.x;
    const int wave = tid >> 6, lane = tid & 63;
    const int t0 = blockIdx.x << 2;      // first 16-col m-tile of this block
    const int m0 = t0 << 4;

    // stage B tile (fragment order is linear -> coalesced)
    #pragma unroll
    for (int i = 0; i < 4; ++i) {
        int e = i * 512 + tid;           // 2048 half8 entries per array
        int tl = t0 + (e >> 9);
        half8 vh = {0, 0, 0, 0, 0, 0, 0, 0};
        half8 vl = {0, 0, 0, 0, 0, 0, 0, 0};
        if (tl < Mtiles) {
            vh = nt_load_h8(&Bh[(long)t0 * 512 + e]);
            vl = nt_load_h8(&Bl[(long)t0 * 512 + e]);
        }
        sB[0][e] = vh;
        sB[1][e] = vl;
    }
    __syncthreads();

    // ---- retrieve passes: 8 passes x 2 q-tiles per wave ----
    #pragma unroll 1
    for (int p = 0; p < 8; ++p) {
        const int qt0 = (p * 8 + wave) * 2;
        const int q0 = qt0 << 4;
        const float* p0 = &qf[(long)(q0 + (lane & 15)) * 256 + ((lane >> 4) << 3)];
        const float* p1 = p0 + 16 * 256;

        floatx4 accH[2][4], accMa[2][4], accMb[2][4];
        #pragma unroll
        for (int tq = 0; tq < 2; ++tq)
            #pragma unroll
            for (int nt = 0; nt < 4; ++nt) {
                accH[tq][nt]  = (floatx4){0.f, 0.f, 0.f, 0.f};
                accMa[tq][nt] = (floatx4){0.f, 0.f, 0.f, 0.f};
                accMb[tq][nt] = (floatx4){0.f, 0.f, 0.f, 0.f};
            }

        f4v r0a = *(const f4v*)p0, r0b = *(const f4v*)(p0 + 4);
        f4v r1a = *(const f4v*)p1, r1b = *(const f4v*)(p1 + 4);

        for (int kc = 0; kc < 8; ++kc) {
            f4v n0a, n0b, n1a, n1b;
            if (kc < 7) {
                const float* q0p = p0 + (kc + 1) * 32;
                const float* q1p = p1 + (kc + 1) * 32;
                n0a = *(const f4v*)q0p; n0b = *(const f4v*)(q0p + 4);
                n1a = *(const f4v*)q1p; n1b = *(const f4v*)(q1p + 4);
            }
            half8 a0h, a0l, a1h, a1l;
            split8r(r0a, r0b, a0h, a0l);
            split8r(r1a, r1b, a1h, a1l);
            #pragma unroll
            for (int nt = 0; nt < 4; ++nt) {
                half8 bh = sB[0][(nt * 8 + kc) * 64 + lane];
                half8 bl = sB[1][(nt * 8 + kc) * 64 + lane];
                accH[0][nt]  = __builtin_amdgcn_mfma_f32_16x16x32_f16(a0h, bh, accH[0][nt],  0, 0, 0);
                accMa[0][nt] = __builtin_amdgcn_mfma_f32_16x16x32_f16(a0h, bl, accMa[0][nt], 0, 0, 0);
                accMb[0][nt] = __builtin_amdgcn_mfma_f32_16x16x32_f16(a0l, bh, accMb[0][nt], 0, 0, 0);
                accH[1][nt]  = __builtin_amdgcn_mfma_f32_16x16x32_f16(a1h, bh, accH[1][nt],  0, 0, 0);
                accMa[1][nt] = __builtin_amdgcn_mfma_f32_16x16x32_f16(a1h, bl, accMa[1][nt], 0, 0, 0);
                accMb[1][nt] = __builtin_amdgcn_mfma_f32_16x16x32_f16(a1l, bh, accMb[1][nt], 0, 0, 0);
            }
            r0a = n0a; r0b = n0b; r1a = n1a; r1b = n1b;
        }

        unsigned long long best[2][4];
        #pragma unroll
        for (int tq = 0; tq < 2; ++tq)
            #pragma unroll
            for (int r = 0; r < 4; ++r) best[tq][r] = 0ULL;

        #pragma unroll
        for (int nt = 0; nt < 4; ++nt) {
            int mi = m0 + (nt << 4) + (lane & 15);
            if (mi < M) {
                unsigned lowbits = ~(unsigned)mi;
                #pragma unroll
                for (int tq = 0; tq < 2; ++tq)
                    #pragma unroll
                    for (int r = 0; r < 4; ++r) {
                        float s = accH[tq][nt][r] +
                                  (accMa[tq][nt][r] + accMb[tq][nt][r]) * (1.0f / 2048.0f);
                        unsigned long long key =
                            (((unsigned long long)fmap(s)) << 32) | lowbits;
                        if (key > best[tq][r]) best[tq][r] = key;
                    }
            }
        }
        #pragma unroll
        for (int tq = 0; tq < 2; ++tq)
            #pragma unroll
            for (int r = 0; r < 4; ++r) {
                unsigned long long b = best[tq][r];
                #pragma unroll
                for (int o = 1; o < 16; o <<= 1) {
                    unsigned long long ob = shfl_xor_u64(b, o);
                    if (ob > b) b = ob;
                }
                if ((lane & 15) == 0) {
                    int q = (qt0 + tq) * 16 + ((lane >> 4) << 2) + r;
                    if (b > packed[q]) atomicMax(&packed[q], b);
                }
            }
    }

    // ---- fused update pass: wave w handles update q-tile w ----
    if (wave * 16 < B) {
        const int u0 = wave << 4;
        const float* pu = &uf[(long)(u0 + (lane & 15)) * 256 + ((lane >> 4) << 3)];

        floatx4 accH[4], accMa[4], accMb[4];
        #pragma unroll
        for (int nt = 0; nt < 4; ++nt) {
            accH[nt]  = (floatx4){0.f, 0.f, 0.f, 0.f};
            accMa[nt] = (floatx4){0.f, 0.f, 0.f, 0.f};
            accMb[nt] = (floatx4){0.f, 0.f, 0.f, 0.f};
        }
        f4v ra = *(const f4v*)pu, rb = *(const f4v*)(pu + 4);
        for (int kc = 0; kc < 8; ++kc) {
            f4v na, nb;
            if (kc < 7) {
                const float* qp = pu + (kc + 1) * 32;
                na = *(const f4v*)qp; nb = *(const f4v*)(qp + 4);
            }
            half8 uh, ul_;
            split8r(ra, rb, uh, ul_);
            #pragma unroll
            for (int nt = 0; nt < 4; ++nt) {
                half8 bh = sB[0][(nt * 8 + kc) * 64 + lane];
                half8 bl = sB[1][(nt * 8 + kc) * 64 + lane];
                accH[nt]  = __builtin_amdgcn_mfma_f32_16x16x32_f16(uh,  bh, accH[nt],  0, 0, 0);
                accMa[nt] = __builtin_amdgcn_mfma_f32_16x16x32_f16(uh,  bl, accMa[nt], 0, 0, 0);
                accMb[nt] = __builtin_amdgcn_mfma_f32_16x16x32_f16(ul_, bh, accMb[nt], 0, 0, 0);
            }
            ra = na; rb = nb;
        }
        int lb[4];
        #pragma unroll
        for (int r = 0; r < 4; ++r) lb[r] = lbl[u0 + ((lane >> 4) << 2) + r];

        unsigned bmax[4];
        unsigned long long ball[4], bsame[4];
        #pragma unroll
        for (int r = 0; r < 4; ++r) { bmax[r] = 0u; ball[r] = ~0ULL; bsame[r] = ~0ULL; }

        #pragma unroll
        for (int nt = 0; nt < 4; ++nt) {
            int mi = m0 + (nt << 4) + (lane & 15);
            if (mi < M) {
                int mvv = mv[mi];
                #pragma unroll
                for (int r = 0; r < 4; ++r) {
                    float s = accH[nt][r] + (accMa[nt][r] + accMb[nt][r]) * (1.0f / 2048.0f);
                    unsigned ms = fmap(s);
                    if (ms > bmax[r]) bmax[r] = ms;
                    unsigned long long key = (((unsigned long long)ms) << 32) | (unsigned)mi;
                    if (key < ball[r]) ball[r] = key;
                    if (mvv == lb[r] && key < bsame[r]) bsame[r] = key;
                }
            }
        }
        #pragma unroll
        for (int r = 0; r < 4; ++r) {
            unsigned bm = bmax[r];
            unsigned long long ba = ball[r], bs = bsame[r];
            #pragma unroll
            for (int o = 1; o < 16; o <<= 1) {
                unsigned om = __shfl_xor(bm, o, 64);
                if (om > bm) bm = om;
                unsigned long long oa = shfl_xor_u64(ba, o);
                if (oa < ba) ba = oa;
                unsigned long long os = shfl_xor_u64(bs, o);
                if (os < bs) bs = os;
            }
            if ((lane & 15) == 0) {
                int b = u0 + ((lane >> 4) << 2) + r;
                if (bm > maxsim[b]) atomicMax(&maxsim[b], bm);
                if (ba < minall[b]) atomicMin(&minall[b], ba);
                if (bs < minsame[b]) atomicMin(&minsame[b], bs);
            }
        }
    }
}

// ---------- finish / output kernels ----------

__global__ void finish_retrieve(const unsigned long long* __restrict__ packed,
                                const int* __restrict__ memvals,
                                const float* __restrict__ rq,
                                float* __restrict__ out, int Q) {
    int q = blockIdx.x * blockDim.x + threadIdx.x;
    if (q >= Q) return;
    unsigned long long key = packed[q];
    unsigned m = ~((unsigned)(key & 0xFFFFFFFFu));
    float conf = funmap((unsigned)(key >> 32)) * rq[q];   // apply row norm here
    out[q] = (float)memvals[m];
    out[Q + q] = conf;
}

__global__ void finish_upd(const unsigned* __restrict__ maxsim,
                           const unsigned long long* __restrict__ minall,
                           const unsigned long long* __restrict__ minsame,
                           const float* __restrict__ ru,
                           int* __restrict__ wtgt, int B) {
    __shared__ int tg[256];
    __shared__ unsigned char du[256];
    int b = threadIdx.x;
    int t = -1; bool d = false;
    if (b < B) {
        d = funmap(maxsim[b]) * ru[b] < 0.8f;             // apply row norm here
        unsigned long long ks = minsame[b];
        unsigned long long ka = minall[b];
        t = (ks != ~0ULL) ? (int)(ks & 0xFFFFFFFFu) : (int)(ka & 0xFFFFFFFFu);
        tg[b] = t; du[b] = d ? 1 : 0;
    }
    __syncthreads();
    if (b < B) {
        bool win = d;
        if (win)
            for (int b2 = b + 1; b2 < B; ++b2)
                if (du[b2] && tg[b2] == t) { win = false; break; }
        wtgt[b] = win ? t : -1;
    }
}

__global__ void copy_keys(const f4v* __restrict__ src, f4v* __restrict__ dst, long n4) {
    long i = blockIdx.x * (long)blockDim.x + threadIdx.x;
    long stride = (long)gridDim.x * blockDim.x;
    for (; i < n4; i += stride) nt_store_f4(nt_load_f4(&src[i]), &dst[i]);
}

__global__ void copy_vals(const int* __restrict__ src, float* __restrict__ dst, int n) {
    int i = blockIdx.x * blockDim.x + threadIdx.x;
    if (i < n) dst[i] = (float)src[i];
}

__global__ void scatter_kernel(const int* __restrict__ wtgt, const float4* __restrict__ upd4,
                               const int* __restrict__ lbl, float4* __restrict__ keys4,
                               float* __restrict__ vals) {
    int b = blockIdx.x;
    int t = wtgt[b];
    if (t < 0) return;
    int l = threadIdx.x; // 64 threads x float4 = 256 floats
    keys4[(long)t * 64 + l] = upd4[(long)b * 64 + l];
    if (l == 0) vals[t] = (float)lbl[b];
}

// ---------- launch ----------

extern "C" void kernel_launch(void* const* d_in, const int* in_sizes, int n_in,
                              void* d_out, int out_size, void* d_ws, size_t ws_size,
                              hipStream_t stream) {
    const float* qf = (const float*)d_in[0];
    const float* mk = (const float*)d_in[1];
    const int*   mv = (const int*)d_in[2];
    const float* uf = (const float*)d_in[3];
    const int*   ul = (const int*)d_in[4];

    const int D = 256;
    const int Q = in_sizes[0] / D;   // 2048
    const int M = in_sizes[2];       // 100000
    const int B = in_sizes[3] / D;   // 128

    float* out = (float*)d_out;
    float* out_keys = out + 2 * (long)Q;
    float* out_vals = out_keys + (long)M * D;

    // B fragment arrays live in the out_keys region (exact fit). copy_keys
    // overwrites them afterwards.
    _Float16* Bh = (_Float16*)out_keys;
    _Float16* Bl = Bh + (size_t)M * D;

    // Reduction scratch + norms live in the out_vals region (cacheable d_out,
    // unlike d_ws whose reads bypass L2). copy_vals overwrites at the end.
    char* ov = (char*)out_vals;
    unsigned long long* packed  = (unsigned long long*)(ov);            // 16 KB
    unsigned long long* minall  = (unsigned long long*)(ov + 16384);    // 1 KB
    unsigned long long* minsame = (unsigned long long*)(ov + 17408);    // 1 KB
    unsigned* maxsim            = (unsigned*)(ov + 18432);              // 0.5 KB
    float* rq                   = (float*)(ov + 18944);                 // 8 KB
    float* ru                   = (float*)(ov + 27136);                 // 0.5 KB

    // d_ws only holds atomic-free, rarely-touched data.
    int* wtgt = (int*)d_ws;

    const int Mtiles = (M + 15) / 16;          // 6250
    const int grid_g = (Mtiles + 3) / 4;       // 1563

    int initN = (Q > B ? Q : B);
    init_kernel<<<(initN + 255) / 256, 256, 0, stream>>>(packed, maxsim, minall, minsame, Q, B);

    norms_kernel<<<(Q + 3) / 4, 256, 0, stream>>>(qf, rq, Q);
    norms_kernel<<<(B + 3) / 4, 256, 0, stream>>>(uf, ru, B);

    prep_b<<<Mtiles, 256, 0, stream>>>(mk, Bh, Bl, M);

    retrieve_fused<<<grid_g, 512, 0, stream>>>(
        qf, uf, (const half8*)Bh, (const half8*)Bl, mv, ul,
        packed, maxsim, minall, minsame, M, Mtiles, B);

    finish_retrieve<<<(Q + 255) / 256, 256, 0, stream>>>(packed, mv, rq, out, Q);
    finish_upd<<<1, B, 0, stream>>>(maxsim, minall, minsame, ru, wtgt, B);

    // Overwrite scratch regions with the real outputs (stream-ordered).
    copy_keys<<<2048, 256, 0, stream>>>((const f4v*)mk, (f4v*)out_keys, (long)M * (D / 4));
    copy_vals<<<(M + 255) / 256, 256, 0, stream>>>(mv, out_vals, M);
    scatter_kernel<<<B, 64, 0, stream>>>(wtgt, (const float4*)uf, ul, (float4*)out_keys, out_vals);
}